// Round 5
// baseline (1130.474 us; speedup 1.0000x reference)
//
#include <hip/hip_runtime.h>
#include <hip/hip_bf16.h>
#include <math.h>

#define E 768
#define NH 12
#define HD 64
#define NTHR 256
#define SLICES 4   // tail: blocks per batch, each owns a row-contiguous slice

typedef __attribute__((ext_vector_type(8))) short bf16x8;
typedef __attribute__((ext_vector_type(4))) float f32x4;

__device__ __forceinline__ unsigned short f2bf_rne(float f) {
    unsigned int u = __float_as_uint(f);
    u += 0x7FFF + ((u >> 16) & 1);   // round-to-nearest-even
    return (unsigned short)(u >> 16);
}

// ---------------------------------------------------------------------------
// Trilinear sample of one (b,p) point -> sampled[u*E..), bf16. (R4-verified)
// ---------------------------------------------------------------------------
__device__ __forceinline__ void sample_one(
    const float* x, const float* bcrd, const float* offs, int G,
    unsigned short* sampled, int u, int P, int fullN, int t, int tstep)
{
    int b = u / P, p = u % P;
    float gm1 = (float)(G - 1);

    float cx = bcrd[p * 3 + 0] + offs[u * 3 + 0];
    float cy = bcrd[p * 3 + 1] + offs[u * 3 + 1];
    float cz = bcrd[p * 3 + 2] + offs[u * 3 + 2];
    cx = fminf(fmaxf(cx, -1.f), 1.f);
    cy = fminf(fmaxf(cy, -1.f), 1.f);
    cz = fminf(fmaxf(cz, -1.f), 1.f);

    float ix = (cx + 1.f) * 0.5f * gm1;
    float iy = (cy + 1.f) * 0.5f * gm1;
    float iz = (cz + 1.f) * 0.5f * gm1;
    float fx = floorf(ix), fy = floorf(iy), fz = floorf(iz);
    float wx = ix - fx, wy = iy - fy, wz = iz - fz;

    int x0 = (int)fminf(fmaxf(fx,       0.f), gm1);
    int x1 = (int)fminf(fmaxf(fx + 1.f, 0.f), gm1);
    int y0 = (int)fminf(fmaxf(fy,       0.f), gm1);
    int y1 = (int)fminf(fmaxf(fy + 1.f, 0.f), gm1);
    int z0 = (int)fminf(fmaxf(fz,       0.f), gm1);
    int z1 = (int)fminf(fmaxf(fz + 1.f, 0.f), gm1);

    int tk[8];
    tk[0] = (z0 * G + y0) * G + x0;
    tk[1] = (z0 * G + y0) * G + x1;
    tk[2] = (z0 * G + y1) * G + x0;
    tk[3] = (z0 * G + y1) * G + x1;
    tk[4] = (z1 * G + y0) * G + x0;
    tk[5] = (z1 * G + y0) * G + x1;
    tk[6] = (z1 * G + y1) * G + x0;
    tk[7] = (z1 * G + y1) * G + x1;
    float wgt[8];
    wgt[0] = (1.f - wz) * (1.f - wy) * (1.f - wx);
    wgt[1] = (1.f - wz) * (1.f - wy) * wx;
    wgt[2] = (1.f - wz) * wy * (1.f - wx);
    wgt[3] = (1.f - wz) * wy * wx;
    wgt[4] = wz * (1.f - wy) * (1.f - wx);
    wgt[5] = wz * (1.f - wy) * wx;
    wgt[6] = wz * wy * (1.f - wx);
    wgt[7] = wz * wy * wx;

    const float4* xb4 = (const float4*)(x + ((size_t)b * fullN + 1) * E);
    ushort4* outp = (ushort4*)(sampled + (size_t)u * E);
    for (int c4 = t; c4 < E / 4; c4 += tstep) {
        float4 acc = {0.f, 0.f, 0.f, 0.f};
#pragma unroll
        for (int k = 0; k < 8; ++k) {
            float4 v = xb4[(size_t)tk[k] * (E / 4) + c4];
            acc.x += wgt[k] * v.x; acc.y += wgt[k] * v.y;
            acc.z += wgt[k] * v.z; acc.w += wgt[k] * v.w;
        }
        ushort4 o;
        o.x = f2bf_rne(acc.x); o.y = f2bf_rne(acc.y);
        o.z = f2bf_rne(acc.z); o.w = f2bf_rne(acc.w);
        outp[c4] = o;
    }
}

// ---------------------------------------------------------------------------
// 64x64 bf16 MFMA NT tile, fp32 out (R4-verified structure).
// ---------------------------------------------------------------------------
__device__ __forceinline__ void gemm64_tile(
    const unsigned short* A, const unsigned short* W,
    const float* bias, float* C,
    int N, int K, int m0, int n0,
    unsigned short* lsA, unsigned short* lsB)
{
    int wv = threadIdx.x >> 6;
    int ln = threadIdx.x & 63;
    int wm = (wv & 1) * 32;
    int wn = (wv >> 1) * 32;

    f32x4 acc[2][2] = {};

    int srow = ln >> 2;        // 0..15
    int scol = (ln & 3) * 8;   // 0,8,16,24

    for (int k0 = 0; k0 < K; k0 += 32) {
        int row = wv * 16 + srow;
        const unsigned short* ga = A + (size_t)(m0 + row) * K + k0 + scol;
        const unsigned short* gw = W + (size_t)(n0 + row) * K + k0 + scol;
        __builtin_amdgcn_global_load_lds(
            (const __attribute__((address_space(1))) unsigned int*)ga,
            (__attribute__((address_space(3))) unsigned int*)(lsA + wv * 16 * 32),
            16, 0, 0);
        __builtin_amdgcn_global_load_lds(
            (const __attribute__((address_space(1))) unsigned int*)gw,
            (__attribute__((address_space(3))) unsigned int*)(lsB + wv * 16 * 32),
            16, 0, 0);
        __syncthreads();

        int kq = (ln >> 4) * 8;
        int rsel = ln & 15;
        bf16x8 af[2], bfr[2];
#pragma unroll
        for (int i = 0; i < 2; ++i) {
            af[i]  = *(const bf16x8*)&lsA[(wm + i * 16 + rsel) * 32 + kq];
            bfr[i] = *(const bf16x8*)&lsB[(wn + i * 16 + rsel) * 32 + kq];
        }
#pragma unroll
        for (int i = 0; i < 2; ++i)
#pragma unroll
            for (int j = 0; j < 2; ++j)
                acc[i][j] = __builtin_amdgcn_mfma_f32_16x16x32_bf16(
                    af[i], bfr[j], acc[i][j], 0, 0, 0);
        __syncthreads();
    }

    int cr = (ln >> 4) * 4;
    int cc = ln & 15;
#pragma unroll
    for (int j = 0; j < 2; ++j) {
        int col = n0 + wn + j * 16 + cc;
        float bv = bias[col];
#pragma unroll
        for (int i = 0; i < 2; ++i) {
#pragma unroll
            for (int r = 0; r < 4; ++r) {
                int row = m0 + wm + i * 16 + cr + r;
                C[(size_t)row * N + col] = acc[i][j][r] + bv;
            }
        }
    }
}

// ---------------------------------------------------------------------------
// W2 tile: W2[n0+64)[k0+64) = Wkv[n,:] @ spw[:,k], bf16 out. (R4-verified)
// ---------------------------------------------------------------------------
__device__ __forceinline__ void w2_tile(
    const float* Wkv, const float* spw, unsigned short* w2_bf,
    int n0, int k0, unsigned short* lsA, unsigned short* lsB)
{
    int t = threadIdx.x;
    int wv = t >> 6;
    int ln = t & 63;
    int wm = (wv & 1) * 32;
    int wn = (wv >> 1) * 32;

    f32x4 acc[2][2] = {};

    for (int j0 = 0; j0 < E; j0 += 32) {
#pragma unroll
        for (int rep = 0; rep < 2; ++rep) {
            int fi = t + rep * 256;
            int r = fi >> 3, c4 = fi & 7;
            float4 v = *(const float4*)(Wkv + (size_t)(n0 + r) * E + j0 + c4 * 4);
            ushort4 o;
            o.x = f2bf_rne(v.x); o.y = f2bf_rne(v.y);
            o.z = f2bf_rne(v.z); o.w = f2bf_rne(v.w);
            *(ushort4*)(lsA + r * 32 + c4 * 4) = o;
        }
#pragma unroll
        for (int rep = 0; rep < 2; ++rep) {
            int fi = t + rep * 256;
            int kk = fi >> 3, j4 = fi & 7;
            const float* sp = spw + (size_t)(j0 + j4 * 4) * E + k0 + kk;
            ushort4 o;
            o.x = f2bf_rne(sp[0 * E]);
            o.y = f2bf_rne(sp[1 * E]);
            o.z = f2bf_rne(sp[2 * E]);
            o.w = f2bf_rne(sp[3 * E]);
            *(ushort4*)(lsB + kk * 32 + j4 * 4) = o;
        }
        __syncthreads();

        int kq = (ln >> 4) * 8;
        int rsel = ln & 15;
        bf16x8 af[2], bfr[2];
#pragma unroll
        for (int i = 0; i < 2; ++i) {
            af[i]  = *(const bf16x8*)&lsA[(wm + i * 16 + rsel) * 32 + kq];
            bfr[i] = *(const bf16x8*)&lsB[(wn + i * 16 + rsel) * 32 + kq];
        }
#pragma unroll
        for (int i = 0; i < 2; ++i)
#pragma unroll
            for (int j = 0; j < 2; ++j)
                acc[i][j] = __builtin_amdgcn_mfma_f32_16x16x32_bf16(
                    af[i], bfr[j], acc[i][j], 0, 0, 0);
        __syncthreads();
    }

    int cr = (ln >> 4) * 4;
    int cc = ln & 15;
#pragma unroll
    for (int j = 0; j < 2; ++j) {
        int col = k0 + wn + j * 16 + cc;
#pragma unroll
        for (int i = 0; i < 2; ++i) {
#pragma unroll
            for (int r = 0; r < 4; ++r) {
                int row = n0 + wm + i * 16 + cr + r;
                w2_bf[(size_t)row * E + col] = f2bf_rne(acc[i][j][r]);
            }
        }
    }
}

// Wave-per-output matvec: C[u] = A[u/N,:] . W[u%N,:] + bias[u%N]  (verified)
__device__ __forceinline__ void matvec_wave(
    const float* A, const float* W, const float* bias, float* C,
    int u, int N, int K, int ln)
{
    int m = u / N, n = u % N;
    const float* a = A + (size_t)m * K;
    const float* w = W + (size_t)n * K;
    float s = 0.f;
    for (int k = ln; k < K; k += 64) s += a[k] * w[k];
#pragma unroll
    for (int off = 32; off; off >>= 1) s += __shfl_down(s, off);
    if (ln == 0) C[u] = s + bias[n];
}

// ---------------------------------------------------------------------------
// K1 "prep": sampling + W2 GEMM + q-proj + b2, all independent segments.
// (R4-verified)
// ---------------------------------------------------------------------------
__global__ __launch_bounds__(256) void prep_kernel(
    const float* __restrict__ x,
    const float* __restrict__ bcrd, const float* __restrict__ offs,
    const int* __restrict__ gsize,
    const float* __restrict__ bio,
    const float* __restrict__ spw, const float* __restrict__ spb,
    const float* __restrict__ ipw, const float* __restrict__ ipb,
    unsigned short* __restrict__ sampled_bf, unsigned short* __restrict__ w2_bf,
    float* __restrict__ q, float* __restrict__ b2,
    int B, int P, int fullN, int nb_sample, int nb_w2, int nb_q)
{
    __shared__ unsigned short lsA[64 * 32];
    __shared__ unsigned short lsB[64 * 32];

    int blk = blockIdx.x;
    int t = threadIdx.x;
    int wv = t >> 6, ln = t & 63;
    const float* Wkv = ipw + (size_t)E * E;

    if (blk < nb_sample) {
        sample_one(x, bcrd, offs, *gsize, sampled_bf, blk, P, fullN, t, NTHR);
        return;
    }
    blk -= nb_sample;
    if (blk < nb_w2) {
        w2_tile(Wkv, spw, w2_bf, (blk / 12) * 64, (blk % 12) * 64, lsA, lsB);
        return;
    }
    blk -= nb_w2;
    if (blk < nb_q) {
        int u = blk * 4 + wv;
        if (u < B * E) matvec_wave(bio, ipw, ipb, q, u, E, E, ln);
        return;
    }
    blk -= nb_q;
    {
        int u = blk * 4 + wv;
        if (u < 2 * E) matvec_wave(spb, Wkv, ipb + E, b2, u, 2 * E, E, ln);
    }
}

// ---------------------------------------------------------------------------
// K2: kv = sampled_bf @ W2^T + b2   (2048 x 1536, K=768, fp32 out)
// ---------------------------------------------------------------------------
__global__ __launch_bounds__(256) void kv_gemm(
    const unsigned short* __restrict__ A,
    const unsigned short* __restrict__ W,
    const float* __restrict__ bias,
    float* __restrict__ C, int N, int K)
{
    __shared__ unsigned short lsA[64 * 32];
    __shared__ unsigned short lsB[64 * 32];
    gemm64_tile(A, W, bias, C, N, K, blockIdx.y * 64, blockIdx.x * 64, lsA, lsB);
}

// ---------------------------------------------------------------------------
// K3 "tail" v2: B*SLICES blocks; block (b,g) computes full attention + FULL
// out-proj for batch b (redundant x SLICES -> 576 MB L2 reads total, ~17us),
// then writes the ROW-CONTIGUOUS slice out[b, g*129 .. , :] with coalesced
// nontemporal float4 stores (writes don't pollute L2 for other blocks'
// out-proj reads). Replaces R4's 96-column-sliced writes (384B segments @
// 3072B stride, 713 GB/s measured).
// ---------------------------------------------------------------------------
__global__ __launch_bounds__(256) void tail_kernel(
    const float* __restrict__ q, const float* __restrict__ kv,
    const float* __restrict__ opw, const float* __restrict__ opb,
    const float* __restrict__ conf, float* __restrict__ out,
    int B, int P, int fullN)
{
    __shared__ float ctx_lds[E];
    __shared__ float aout_lds[E];   // conf-scaled

    int b = blockIdx.x % B;         // consecutive blocks -> different XCDs;
    int g = blockIdx.x / B;         // all slices of batch b on same XCD (kv L2-local)
    int t = threadIdx.x, wv = t >> 6, ln = t & 63;

    const float* kvb = kv + (size_t)b * P * (2 * E);

    // ---- attention: wave wv handles heads wv, wv+4, wv+8 (R4-verified) ----
    for (int h = wv; h < NH; h += 4) {
        float qd = q[(size_t)b * E + h * HD + ln];
        int krow = (ln < P) ? ln : 0;
        const float* kr = kvb + (size_t)krow * (2 * E) + h * HD;
        float accd = 0.f;
#pragma unroll
        for (int e = 0; e < HD; ++e) accd += __shfl(qd, e) * kr[e];
        float s = (ln < P) ? accd * 0.125f : -INFINITY;

        float mx = s;
#pragma unroll
        for (int off = 32; off; off >>= 1) mx = fmaxf(mx, __shfl_xor(mx, off));
        float ex = (ln < P) ? __expf(s - mx) : 0.f;
        float den = ex;
#pragma unroll
        for (int off = 32; off; off >>= 1) den += __shfl_xor(den, off);
        float pl = ex / den;

        float acc = 0.f;
        for (int p = 0; p < P; ++p)
            acc += __shfl(pl, p) * kvb[(size_t)p * (2 * E) + E + h * HD + ln];
        ctx_lds[h * HD + ln] = acc;
    }
    __syncthreads();

    // ---- full out-proj: wave wv owns n in [wv*192, wv*192+192) ------------
    float cf = conf[b];
#pragma unroll 2
    for (int idx = 0; idx < 192; ++idx) {
        int n = wv * 192 + idx;
        const float* w = opw + (size_t)n * E;
        float s = 0.f;
        for (int k = ln; k < E; k += 64) s += ctx_lds[k] * w[k];
#pragma unroll
        for (int off = 32; off; off >>= 1) s += __shfl_down(s, off);
        if (ln == 0) aout_lds[n] = (s + opb[n]) * cf;
    }
    __syncthreads();

    // ---- write row-contiguous slice: out[b, r0:rend, :] -------------------
    int rows_per = (fullN + SLICES - 1) / SLICES;     // 129
    int r0 = g * rows_per;
    int rend = r0 + rows_per; if (rend > fullN) rend = fullN;
    int n4 = (rend - r0) * (E / 4);                   // float4 count

    const f32x4* a4 = (const f32x4*)aout_lds;
    f32x4* ob = (f32x4*)(out + ((size_t)b * fullN + r0) * E);
    int c4 = (t >= 192) ? t - 192 : t;                // t mod 192
    for (int i = t; i < n4; i += NTHR) {
        __builtin_nontemporal_store(a4[c4], &ob[i]);
        c4 += 64; if (c4 >= 192) c4 -= 192;           // (i+256) mod 192
    }
}

// ---------------------------------------------------------------------------
// Path-B tail (fallback if d_ws is too small): R1-proven kernels.
// ---------------------------------------------------------------------------
__global__ void attn_fb(const float* __restrict__ q,
                        const float* __restrict__ kv,
                        float* __restrict__ ctx, int B, int P)
{
    int u = blockIdx.x * 4 + (threadIdx.x >> 6);
    int ln = threadIdx.x & 63;
    if (u >= B * NH) return;
    int b = u / NH, h = u % NH;
    float qd = q[(size_t)b * E + h * HD + ln];
    const float* kvb = kv + (size_t)b * P * (2 * E);
    int krow = (ln < P) ? ln : 0;
    const float* kr = kvb + (size_t)krow * (2 * E) + h * HD;
    float accd = 0.f;
#pragma unroll
    for (int e = 0; e < HD; ++e) accd += __shfl(qd, e) * kr[e];
    float s = (ln < P) ? accd * 0.125f : -INFINITY;
    float mx = s;
#pragma unroll
    for (int off = 32; off; off >>= 1) mx = fmaxf(mx, __shfl_xor(mx, off));
    float ex = (ln < P) ? __expf(s - mx) : 0.f;
    float den = ex;
#pragma unroll
    for (int off = 32; off; off >>= 1) den += __shfl_xor(den, off);
    float pl = ex / den;
    float acc = 0.f;
    for (int p = 0; p < P; ++p)
        acc += __shfl(pl, p) * kvb[(size_t)p * (2 * E) + E + h * HD + ln];
    ctx[(size_t)b * E + h * HD + ln] = acc;
}

__global__ void matvec_fb(const float* __restrict__ A,
                          const float* __restrict__ W,
                          const float* __restrict__ bias,
                          float* __restrict__ C, int M, int N, int K)
{
    int u = blockIdx.x * 4 + (threadIdx.x >> 6);
    if (u < M * N) matvec_wave(A, W, bias, C, u, N, K, threadIdx.x & 63);
}

__global__ void bcast_kernel(const float* __restrict__ attn_out,
                             const float* __restrict__ conf,
                             float* __restrict__ out,
                             int fullN, int pc)
{
    int b = blockIdx.y;
    float cf = conf[b];
    const float4* ao = (const float4*)(attn_out + (size_t)b * E);
    float4* ob = (float4*)(out + (size_t)b * fullN * E);
    int i = blockIdx.x * blockDim.x + threadIdx.x;
    if (i < pc) {
        int c4 = i % (E / 4);
        float4 v = ao[c4];
        v.x *= cf; v.y *= cf; v.z *= cf; v.w *= cf;
        ob[i] = v;
    }
}

// ---------------------------------------------------------------------------
extern "C" void kernel_launch(void* const* d_in, const int* in_sizes, int n_in,
                              void* d_out, int out_size, void* d_ws, size_t ws_size,
                              hipStream_t stream)
{
    const float* x      = (const float*)d_in[0];
    const float* bio    = (const float*)d_in[1];
    const float* bcrd   = (const float*)d_in[2];
    const float* offs   = (const float*)d_in[3];
    const float* conf   = (const float*)d_in[4];
    const float* spw    = (const float*)d_in[5];
    const float* spb    = (const float*)d_in[6];
    const float* ipw    = (const float*)d_in[7];
    const float* ipb    = (const float*)d_in[8];
    const float* opw    = (const float*)d_in[9];
    const float* opb    = (const float*)d_in[10];
    const int*   gsize  = (const int*)d_in[11];
    float* out = (float*)d_out;

    int B     = in_sizes[1] / E;            // 64
    int P     = in_sizes[2] / 3;            // 32
    int fullN = in_sizes[0] / (B * E);      // 513
    int M     = B * P;                      // 2048

    // sampled_bf / w2_bf stay in d_out's front (only read by K1/K2, and
    // fully overwritten by the final output writes afterwards).
    char* base = (char*)d_out;
    unsigned short* sampled_bf = (unsigned short*)(base + 0);          // 3.0 MB
    unsigned short* w2_bf      = (unsigned short*)(base + 3145728);    // 2.25 MB

    const size_t kv_bytes = (size_t)M * (2 * E) * 4;        // 12,582,912
    const size_t q_bytes  = (size_t)B * E * 4;              // 196,608
    const size_t b2_bytes = (size_t)(2 * E) * 4;            // 6,144
    const bool path_a = (ws_size >= kv_bytes + q_bytes + b2_bytes);

    float *kv, *q, *b2;
    if (path_a) {
        kv = (float*)d_ws;
        q  = (float*)((char*)d_ws + kv_bytes);
        b2 = (float*)((char*)d_ws + kv_bytes + q_bytes);
    } else {
        kv = (float*)(base + 5505024);                      // 12.6 MB
        q  = (float*)(base + 18087936);                     // 192 KB
        b2 = (float*)(base + 18481152);                     // 6 KB
    }

    // K1: prep (sample + W2 GEMM + q-proj + b2)
    int nb_sample = M;                       // 2048
    int nb_w2     = (2 * E / 64) * (E / 64); // 288
    int nb_q      = (B * E + 3) / 4;         // 12288
    int nb_b2     = (2 * E + 3) / 4;         // 384
    prep_kernel<<<nb_sample + nb_w2 + nb_q + nb_b2, NTHR, 0, stream>>>(
        x, bcrd, offs, gsize, bio, spw, spb, ipw, ipb,
        sampled_bf, w2_bf, q, b2, B, P, fullN, nb_sample, nb_w2, nb_q);

    // K2: kv = sampled @ W2^T + b2
    kv_gemm<<<dim3(2 * E / 64, M / 64), NTHR, 0, stream>>>(
        sampled_bf, w2_bf, b2, kv, 2 * E, E);

    if (path_a) {
        // K3: fused attention + out-proj + row-contiguous broadcast
        tail_kernel<<<B * SLICES, NTHR, 0, stream>>>(q, kv, opw, opb, conf, out,
                                                     B, P, fullN);
    } else {
        // fallback: R1-proven tail (ctx in d_out scratch, aout in d_ws)
        float* ctx  = (float*)(base + 18284544);
        float* aout = (float*)d_ws;                          // 192 KB
        attn_fb<<<(B * NH + 3) / 4, NTHR, 0, stream>>>(q, kv, ctx, B, P);
        matvec_fb<<<(B * E + 3) / 4, NTHR, 0, stream>>>(ctx, opw, opb, aout,
                                                        B, E, E);
        int pc = fullN * E / 4;
        bcast_kernel<<<dim3((pc + 255) / 256, B), NTHR, 0, stream>>>(
            aout, conf, out, fullN, pc);
    }
}

// Round 6
// 393.156 us; speedup vs baseline: 2.8754x; 2.8754x over previous
//
#include <hip/hip_runtime.h>
#include <hip/hip_bf16.h>
#include <math.h>

#define E 768
#define NH 12
#define HD 64
#define NTHR 256
#define SLICES 8   // tail: blocks per batch, each owns a row-contiguous slice

typedef __attribute__((ext_vector_type(8))) short bf16x8;
typedef __attribute__((ext_vector_type(4))) float f32x4;

__device__ __forceinline__ unsigned short f2bf_rne(float f) {
    unsigned int u = __float_as_uint(f);
    u += 0x7FFF + ((u >> 16) & 1);   // round-to-nearest-even
    return (unsigned short)(u >> 16);
}

// ---------------------------------------------------------------------------
// Trilinear sample of one (b,p) point -> sampled[u*E..), bf16. (R4-verified)
// ---------------------------------------------------------------------------
__device__ __forceinline__ void sample_one(
    const float* x, const float* bcrd, const float* offs, int G,
    unsigned short* sampled, int u, int P, int fullN, int t, int tstep)
{
    int b = u / P, p = u % P;
    float gm1 = (float)(G - 1);

    float cx = bcrd[p * 3 + 0] + offs[u * 3 + 0];
    float cy = bcrd[p * 3 + 1] + offs[u * 3 + 1];
    float cz = bcrd[p * 3 + 2] + offs[u * 3 + 2];
    cx = fminf(fmaxf(cx, -1.f), 1.f);
    cy = fminf(fmaxf(cy, -1.f), 1.f);
    cz = fminf(fmaxf(cz, -1.f), 1.f);

    float ix = (cx + 1.f) * 0.5f * gm1;
    float iy = (cy + 1.f) * 0.5f * gm1;
    float iz = (cz + 1.f) * 0.5f * gm1;
    float fx = floorf(ix), fy = floorf(iy), fz = floorf(iz);
    float wx = ix - fx, wy = iy - fy, wz = iz - fz;

    int x0 = (int)fminf(fmaxf(fx,       0.f), gm1);
    int x1 = (int)fminf(fmaxf(fx + 1.f, 0.f), gm1);
    int y0 = (int)fminf(fmaxf(fy,       0.f), gm1);
    int y1 = (int)fminf(fmaxf(fy + 1.f, 0.f), gm1);
    int z0 = (int)fminf(fmaxf(fz,       0.f), gm1);
    int z1 = (int)fminf(fmaxf(fz + 1.f, 0.f), gm1);

    int tk[8];
    tk[0] = (z0 * G + y0) * G + x0;
    tk[1] = (z0 * G + y0) * G + x1;
    tk[2] = (z0 * G + y1) * G + x0;
    tk[3] = (z0 * G + y1) * G + x1;
    tk[4] = (z1 * G + y0) * G + x0;
    tk[5] = (z1 * G + y0) * G + x1;
    tk[6] = (z1 * G + y1) * G + x0;
    tk[7] = (z1 * G + y1) * G + x1;
    float wgt[8];
    wgt[0] = (1.f - wz) * (1.f - wy) * (1.f - wx);
    wgt[1] = (1.f - wz) * (1.f - wy) * wx;
    wgt[2] = (1.f - wz) * wy * (1.f - wx);
    wgt[3] = (1.f - wz) * wy * wx;
    wgt[4] = wz * (1.f - wy) * (1.f - wx);
    wgt[5] = wz * (1.f - wy) * wx;
    wgt[6] = wz * wy * (1.f - wx);
    wgt[7] = wz * wy * wx;

    const float4* xb4 = (const float4*)(x + ((size_t)b * fullN + 1) * E);
    ushort4* outp = (ushort4*)(sampled + (size_t)u * E);
    for (int c4 = t; c4 < E / 4; c4 += tstep) {
        float4 acc = {0.f, 0.f, 0.f, 0.f};
#pragma unroll
        for (int k = 0; k < 8; ++k) {
            float4 v = xb4[(size_t)tk[k] * (E / 4) + c4];
            acc.x += wgt[k] * v.x; acc.y += wgt[k] * v.y;
            acc.z += wgt[k] * v.z; acc.w += wgt[k] * v.w;
        }
        ushort4 o;
        o.x = f2bf_rne(acc.x); o.y = f2bf_rne(acc.y);
        o.z = f2bf_rne(acc.z); o.w = f2bf_rne(acc.w);
        outp[c4] = o;
    }
}

// ---------------------------------------------------------------------------
// 64x64 bf16 MFMA NT tile, fp32 out (R4-verified structure).
// ---------------------------------------------------------------------------
__device__ __forceinline__ void gemm64_tile(
    const unsigned short* A, const unsigned short* W,
    const float* bias, float* C,
    int N, int K, int m0, int n0,
    unsigned short* lsA, unsigned short* lsB)
{
    int wv = threadIdx.x >> 6;
    int ln = threadIdx.x & 63;
    int wm = (wv & 1) * 32;
    int wn = (wv >> 1) * 32;

    f32x4 acc[2][2] = {};

    int srow = ln >> 2;        // 0..15
    int scol = (ln & 3) * 8;   // 0,8,16,24

    for (int k0 = 0; k0 < K; k0 += 32) {
        int row = wv * 16 + srow;
        const unsigned short* ga = A + (size_t)(m0 + row) * K + k0 + scol;
        const unsigned short* gw = W + (size_t)(n0 + row) * K + k0 + scol;
        __builtin_amdgcn_global_load_lds(
            (const __attribute__((address_space(1))) unsigned int*)ga,
            (__attribute__((address_space(3))) unsigned int*)(lsA + wv * 16 * 32),
            16, 0, 0);
        __builtin_amdgcn_global_load_lds(
            (const __attribute__((address_space(1))) unsigned int*)gw,
            (__attribute__((address_space(3))) unsigned int*)(lsB + wv * 16 * 32),
            16, 0, 0);
        __syncthreads();

        int kq = (ln >> 4) * 8;
        int rsel = ln & 15;
        bf16x8 af[2], bfr[2];
#pragma unroll
        for (int i = 0; i < 2; ++i) {
            af[i]  = *(const bf16x8*)&lsA[(wm + i * 16 + rsel) * 32 + kq];
            bfr[i] = *(const bf16x8*)&lsB[(wn + i * 16 + rsel) * 32 + kq];
        }
#pragma unroll
        for (int i = 0; i < 2; ++i)
#pragma unroll
            for (int j = 0; j < 2; ++j)
                acc[i][j] = __builtin_amdgcn_mfma_f32_16x16x32_bf16(
                    af[i], bfr[j], acc[i][j], 0, 0, 0);
        __syncthreads();
    }

    int cr = (ln >> 4) * 4;
    int cc = ln & 15;
#pragma unroll
    for (int j = 0; j < 2; ++j) {
        int col = n0 + wn + j * 16 + cc;
        float bv = bias[col];
#pragma unroll
        for (int i = 0; i < 2; ++i) {
#pragma unroll
            for (int r = 0; r < 4; ++r) {
                int row = m0 + wm + i * 16 + cr + r;
                C[(size_t)row * N + col] = acc[i][j][r] + bv;
            }
        }
    }
}

// ---------------------------------------------------------------------------
// W2 tile: W2[n0+64)[k0+64) = Wkv[n,:] @ spw[:,k], bf16 out. (R4-verified)
// ---------------------------------------------------------------------------
__device__ __forceinline__ void w2_tile(
    const float* Wkv, const float* spw, unsigned short* w2_bf,
    int n0, int k0, unsigned short* lsA, unsigned short* lsB)
{
    int t = threadIdx.x;
    int wv = t >> 6;
    int ln = t & 63;
    int wm = (wv & 1) * 32;
    int wn = (wv >> 1) * 32;

    f32x4 acc[2][2] = {};

    for (int j0 = 0; j0 < E; j0 += 32) {
#pragma unroll
        for (int rep = 0; rep < 2; ++rep) {
            int fi = t + rep * 256;
            int r = fi >> 3, c4 = fi & 7;
            float4 v = *(const float4*)(Wkv + (size_t)(n0 + r) * E + j0 + c4 * 4);
            ushort4 o;
            o.x = f2bf_rne(v.x); o.y = f2bf_rne(v.y);
            o.z = f2bf_rne(v.z); o.w = f2bf_rne(v.w);
            *(ushort4*)(lsA + r * 32 + c4 * 4) = o;
        }
#pragma unroll
        for (int rep = 0; rep < 2; ++rep) {
            int fi = t + rep * 256;
            int kk = fi >> 3, j4 = fi & 7;
            const float* sp = spw + (size_t)(j0 + j4 * 4) * E + k0 + kk;
            ushort4 o;
            o.x = f2bf_rne(sp[0 * E]);
            o.y = f2bf_rne(sp[1 * E]);
            o.z = f2bf_rne(sp[2 * E]);
            o.w = f2bf_rne(sp[3 * E]);
            *(ushort4*)(lsB + kk * 32 + j4 * 4) = o;
        }
        __syncthreads();

        int kq = (ln >> 4) * 8;
        int rsel = ln & 15;
        bf16x8 af[2], bfr[2];
#pragma unroll
        for (int i = 0; i < 2; ++i) {
            af[i]  = *(const bf16x8*)&lsA[(wm + i * 16 + rsel) * 32 + kq];
            bfr[i] = *(const bf16x8*)&lsB[(wn + i * 16 + rsel) * 32 + kq];
        }
#pragma unroll
        for (int i = 0; i < 2; ++i)
#pragma unroll
            for (int j = 0; j < 2; ++j)
                acc[i][j] = __builtin_amdgcn_mfma_f32_16x16x32_bf16(
                    af[i], bfr[j], acc[i][j], 0, 0, 0);
        __syncthreads();
    }

    int cr = (ln >> 4) * 4;
    int cc = ln & 15;
#pragma unroll
    for (int j = 0; j < 2; ++j) {
        int col = k0 + wn + j * 16 + cc;
#pragma unroll
        for (int i = 0; i < 2; ++i) {
#pragma unroll
            for (int r = 0; r < 4; ++r) {
                int row = n0 + wm + i * 16 + cr + r;
                w2_bf[(size_t)row * E + col] = f2bf_rne(acc[i][j][r]);
            }
        }
    }
}

// Generic (rolled) wave dot — fallback path only.
__device__ __forceinline__ void matvec_wave(
    const float* A, const float* W, const float* bias, float* C,
    int u, int N, int K, int ln)
{
    int m = u / N, n = u % N;
    const float* a = A + (size_t)m * K;
    const float* w = W + (size_t)n * K;
    float s = 0.f;
    for (int k = ln; k < K; k += 64) s += a[k] * w[k];
#pragma unroll
    for (int off = 32; off; off >>= 1) s += __shfl_down(s, off);
    if (ln == 0) C[u] = s + bias[n];
}

// Vectorized wave dot for K==768: 3 independent float4 loads per operand
// (explicitly unrolled -> loads overlap; the rolled runtime-start loop above
// serializes ~12 L2 round-trips per dot, which R5 showed costs ~5K cy/dot).
__device__ __forceinline__ void matvec_wave_v4(
    const float* A, const float* W, const float* bias, float* C,
    int u, int N, int ln)
{
    int m = u / N, n = u % N;
    const float4* a4 = (const float4*)(A + (size_t)m * E);
    const float4* w4 = (const float4*)(W + (size_t)n * E);
    float s = 0.f;
#pragma unroll
    for (int j = 0; j < 3; ++j) {
        float4 av = a4[ln + 64 * j];
        float4 wv = w4[ln + 64 * j];
        s += av.x * wv.x + av.y * wv.y + av.z * wv.z + av.w * wv.w;
    }
#pragma unroll
    for (int off = 32; off; off >>= 1) s += __shfl_down(s, off);
    if (ln == 0) C[u] = s + bias[n];
}

// ---------------------------------------------------------------------------
// K1 "prep": sampling + W2 GEMM + q-proj + b2, all independent segments.
// ---------------------------------------------------------------------------
__global__ __launch_bounds__(256) void prep_kernel(
    const float* __restrict__ x,
    const float* __restrict__ bcrd, const float* __restrict__ offs,
    const int* __restrict__ gsize,
    const float* __restrict__ bio,
    const float* __restrict__ spw, const float* __restrict__ spb,
    const float* __restrict__ ipw, const float* __restrict__ ipb,
    unsigned short* __restrict__ sampled_bf, unsigned short* __restrict__ w2_bf,
    float* __restrict__ q, float* __restrict__ b2,
    int B, int P, int fullN, int nb_sample, int nb_w2, int nb_q)
{
    __shared__ unsigned short lsA[64 * 32];
    __shared__ unsigned short lsB[64 * 32];

    int blk = blockIdx.x;
    int t = threadIdx.x;
    int wv = t >> 6, ln = t & 63;
    const float* Wkv = ipw + (size_t)E * E;

    if (blk < nb_sample) {
        sample_one(x, bcrd, offs, *gsize, sampled_bf, blk, P, fullN, t, NTHR);
        return;
    }
    blk -= nb_sample;
    if (blk < nb_w2) {
        w2_tile(Wkv, spw, w2_bf, (blk / 12) * 64, (blk % 12) * 64, lsA, lsB);
        return;
    }
    blk -= nb_w2;
    if (blk < nb_q) {
        int u = blk * 4 + wv;
        if (u < B * E) matvec_wave_v4(bio, ipw, ipb, q, u, E, ln);
        return;
    }
    blk -= nb_q;
    {
        int u = blk * 4 + wv;
        if (u < 2 * E) matvec_wave_v4(spb, Wkv, ipb + E, b2, u, 2 * E, ln);
    }
}

// ---------------------------------------------------------------------------
// K2: kv = sampled_bf @ W2^T + b2   (2048 x 1536, K=768, fp32 out)
// ---------------------------------------------------------------------------
__global__ __launch_bounds__(256) void kv_gemm(
    const unsigned short* __restrict__ A,
    const unsigned short* __restrict__ W,
    const float* __restrict__ bias,
    float* __restrict__ C, int N, int K)
{
    __shared__ unsigned short lsA[64 * 32];
    __shared__ unsigned short lsB[64 * 32];
    gemm64_tile(A, W, bias, C, N, K, blockIdx.y * 64, blockIdx.x * 64, lsA, lsB);
}

// ---------------------------------------------------------------------------
// K3 "tail" v3: B*SLICES=512 blocks (2/CU). Block (b,g): attention (q staged
// in LDS, vectorized K-dot, P=32-unrolled PV) + full out-proj (vectorized
// unrolled dots -> 12 loads in flight, vs R5's rolled loop = serialized L2
// round-trips, the 911us cause) + row-contiguous NT write of ~65 rows.
// ---------------------------------------------------------------------------
__global__ __launch_bounds__(256) void tail_kernel(
    const float* __restrict__ q, const float* __restrict__ kv,
    const float* __restrict__ opw, const float* __restrict__ opb,
    const float* __restrict__ conf, float* __restrict__ out,
    int B, int P, int fullN)
{
    __shared__ __align__(16) float q_lds[E];
    __shared__ __align__(16) float ctx_lds[E];
    __shared__ __align__(16) float aout_lds[E];

    int b = blockIdx.x % B;         // all slices of batch b land on same XCD
    int g = blockIdx.x / B;         // row-slice index 0..SLICES-1
    int t = threadIdx.x, wv = t >> 6, ln = t & 63;

    const float* kvb = kv + (size_t)b * P * (2 * E);

    // stage q[b] (768 floats, coalesced)
    for (int i = t; i < E; i += NTHR) q_lds[i] = q[(size_t)b * E + i];
    __syncthreads();

    // ---- attention: wave wv handles heads wv, wv+4, wv+8 ------------------
    for (int h = wv; h < NH; h += 4) {
        int krow = (ln < P) ? ln : 0;
        const float4* kr4 = (const float4*)(kvb + (size_t)krow * (2 * E) + h * HD);
        const float* qh = q_lds + h * HD;
        float accd = 0.f;
#pragma unroll
        for (int j = 0; j < HD / 4; ++j) {          // 16 independent loads
            float4 k4 = kr4[j];
            accd += qh[4 * j] * k4.x + qh[4 * j + 1] * k4.y
                  + qh[4 * j + 2] * k4.z + qh[4 * j + 3] * k4.w;
        }
        float s = (ln < P) ? accd * 0.125f : -INFINITY;

        float mx = s;
#pragma unroll
        for (int off = 32; off; off >>= 1) mx = fmaxf(mx, __shfl_xor(mx, off));
        float ex = (ln < P) ? __expf(s - mx) : 0.f;
        float den = ex;
#pragma unroll
        for (int off = 32; off; off >>= 1) den += __shfl_xor(den, off);
        float pl = ex / den;

        const float* vcol = kvb + E + h * HD + ln;
        float acc = 0.f;
        if (P == 32) {
#pragma unroll
            for (int p = 0; p < 32; ++p)            // 32 independent loads
                acc += __shfl(pl, p) * vcol[(size_t)p * (2 * E)];
        } else {
            for (int p = 0; p < P; ++p)
                acc += __shfl(pl, p) * vcol[(size_t)p * (2 * E)];
        }
        ctx_lds[h * HD + ln] = acc;
    }
    __syncthreads();

    // ---- full out-proj (conf-scaled), vectorized dots ---------------------
    float cf = conf[b];
    const float4* c4p = (const float4*)ctx_lds;
#pragma unroll 4
    for (int idx = 0; idx < 192; ++idx) {
        int n = wv * 192 + idx;
        const float4* w4 = (const float4*)(opw + (size_t)n * E);
        float s = 0.f;
#pragma unroll
        for (int j = 0; j < 3; ++j) {
            float4 wvv = w4[ln + 64 * j];
            float4 cv = c4p[ln + 64 * j];
            s += wvv.x * cv.x + wvv.y * cv.y + wvv.z * cv.z + wvv.w * cv.w;
        }
#pragma unroll
        for (int off = 32; off; off >>= 1) s += __shfl_down(s, off);
        if (ln == 0) aout_lds[n] = (s + opb[n]) * cf;
    }
    __syncthreads();

    // ---- write row-contiguous slice: out[b, r0:rend, :] -------------------
    int rows_per = (fullN + SLICES - 1) / SLICES;     // 65
    int r0 = g * rows_per;
    int rend = r0 + rows_per; if (rend > fullN) rend = fullN;
    if (r0 >= rend) return;
    int n4 = (rend - r0) * (E / 4);

    const f32x4* a4 = (const f32x4*)aout_lds;
    f32x4* ob = (f32x4*)(out + ((size_t)b * fullN + r0) * E);
    int c4 = (t >= 192) ? t - 192 : t;                // t mod 192
    for (int i = t; i < n4; i += NTHR) {
        __builtin_nontemporal_store(a4[c4], &ob[i]);
        c4 += 64; if (c4 >= 192) c4 -= 192;           // (i+256) mod 192
    }
}

// ---------------------------------------------------------------------------
// Path-B tail (fallback if d_ws is too small): R1-proven kernels.
// ---------------------------------------------------------------------------
__global__ void attn_fb(const float* __restrict__ q,
                        const float* __restrict__ kv,
                        float* __restrict__ ctx, int B, int P)
{
    int u = blockIdx.x * 4 + (threadIdx.x >> 6);
    int ln = threadIdx.x & 63;
    if (u >= B * NH) return;
    int b = u / NH, h = u % NH;
    float qd = q[(size_t)b * E + h * HD + ln];
    const float* kvb = kv + (size_t)b * P * (2 * E);
    int krow = (ln < P) ? ln : 0;
    const float* kr = kvb + (size_t)krow * (2 * E) + h * HD;
    float accd = 0.f;
#pragma unroll
    for (int e = 0; e < HD; ++e) accd += __shfl(qd, e) * kr[e];
    float s = (ln < P) ? accd * 0.125f : -INFINITY;
    float mx = s;
#pragma unroll
    for (int off = 32; off; off >>= 1) mx = fmaxf(mx, __shfl_xor(mx, off));
    float ex = (ln < P) ? __expf(s - mx) : 0.f;
    float den = ex;
#pragma unroll
    for (int off = 32; off; off >>= 1) den += __shfl_xor(den, off);
    float pl = ex / den;
    float acc = 0.f;
    for (int p = 0; p < P; ++p)
        acc += __shfl(pl, p) * kvb[(size_t)p * (2 * E) + E + h * HD + ln];
    ctx[(size_t)b * E + h * HD + ln] = acc;
}

__global__ void matvec_fb(const float* __restrict__ A,
                          const float* __restrict__ W,
                          const float* __restrict__ bias,
                          float* __restrict__ C, int M, int N, int K)
{
    int u = blockIdx.x * 4 + (threadIdx.x >> 6);
    if (u < M * N) matvec_wave(A, W, bias, C, u, N, K, threadIdx.x & 63);
}

__global__ void bcast_kernel(const float* __restrict__ attn_out,
                             const float* __restrict__ conf,
                             float* __restrict__ out,
                             int fullN, int pc)
{
    int b = blockIdx.y;
    float cf = conf[b];
    const float4* ao = (const float4*)(attn_out + (size_t)b * E);
    float4* ob = (float4*)(out + (size_t)b * fullN * E);
    int i = blockIdx.x * blockDim.x + threadIdx.x;
    if (i < pc) {
        int c4 = i % (E / 4);
        float4 v = ao[c4];
        v.x *= cf; v.y *= cf; v.z *= cf; v.w *= cf;
        ob[i] = v;
    }
}

// ---------------------------------------------------------------------------
extern "C" void kernel_launch(void* const* d_in, const int* in_sizes, int n_in,
                              void* d_out, int out_size, void* d_ws, size_t ws_size,
                              hipStream_t stream)
{
    const float* x      = (const float*)d_in[0];
    const float* bio    = (const float*)d_in[1];
    const float* bcrd   = (const float*)d_in[2];
    const float* offs   = (const float*)d_in[3];
    const float* conf   = (const float*)d_in[4];
    const float* spw    = (const float*)d_in[5];
    const float* spb    = (const float*)d_in[6];
    const float* ipw    = (const float*)d_in[7];
    const float* ipb    = (const float*)d_in[8];
    const float* opw    = (const float*)d_in[9];
    const float* opb    = (const float*)d_in[10];
    const int*   gsize  = (const int*)d_in[11];
    float* out = (float*)d_out;

    int B     = in_sizes[1] / E;            // 64
    int P     = in_sizes[2] / 3;            // 32
    int fullN = in_sizes[0] / (B * E);      // 513
    int M     = B * P;                      // 2048

    // sampled_bf / w2_bf stay in d_out's front (only read by K1/K2, and
    // fully overwritten by the final output writes afterwards).
    char* base = (char*)d_out;
    unsigned short* sampled_bf = (unsigned short*)(base + 0);          // 3.0 MB
    unsigned short* w2_bf      = (unsigned short*)(base + 3145728);    // 2.25 MB

    const size_t kv_bytes = (size_t)M * (2 * E) * 4;        // 12,582,912
    const size_t q_bytes  = (size_t)B * E * 4;              // 196,608
    const size_t b2_bytes = (size_t)(2 * E) * 4;            // 6,144
    const bool path_a = (ws_size >= kv_bytes + q_bytes + b2_bytes);

    float *kv, *q, *b2;
    if (path_a) {
        kv = (float*)d_ws;
        q  = (float*)((char*)d_ws + kv_bytes);
        b2 = (float*)((char*)d_ws + kv_bytes + q_bytes);
    } else {
        kv = (float*)(base + 5505024);                      // 12.6 MB
        q  = (float*)(base + 18087936);                     // 192 KB
        b2 = (float*)(base + 18481152);                     // 6 KB
    }

    // K1: prep (sample + W2 GEMM + q-proj + b2)
    int nb_sample = M;                       // 2048
    int nb_w2     = (2 * E / 64) * (E / 64); // 288
    int nb_q      = (B * E + 3) / 4;         // 12288
    int nb_b2     = (2 * E + 3) / 4;         // 384
    prep_kernel<<<nb_sample + nb_w2 + nb_q + nb_b2, NTHR, 0, stream>>>(
        x, bcrd, offs, gsize, bio, spw, spb, ipw, ipb,
        sampled_bf, w2_bf, q, b2, B, P, fullN, nb_sample, nb_w2, nb_q);

    // K2: kv = sampled @ W2^T + b2
    kv_gemm<<<dim3(2 * E / 64, M / 64), NTHR, 0, stream>>>(
        sampled_bf, w2_bf, b2, kv, 2 * E, E);

    if (path_a) {
        // K3: fused attention + out-proj + row-contiguous broadcast
        tail_kernel<<<B * SLICES, NTHR, 0, stream>>>(q, kv, opw, opb, conf, out,
                                                     B, P, fullN);
    } else {
        // fallback: R1-proven tail (ctx in d_out scratch, aout in d_ws)
        float* ctx  = (float*)(base + 18284544);
        float* aout = (float*)d_ws;                          // 192 KB
        attn_fb<<<(B * NH + 3) / 4, NTHR, 0, stream>>>(q, kv, ctx, B, P);
        matvec_fb<<<(B * E + 3) / 4, NTHR, 0, stream>>>(ctx, opw, opb, aout,
                                                        B, E, E);
        int pc = fullN * E / 4;
        bcast_kernel<<<dim3((pc + 255) / 256, B), NTHR, 0, stream>>>(
            aout, conf, out, fullN, pc);
    }
}

// Round 7
// 271.359 us; speedup vs baseline: 4.1660x; 1.4488x over previous
//
#include <hip/hip_runtime.h>
#include <hip/hip_bf16.h>
#include <math.h>

#define E 768
#define NH 12
#define HD 64
#define NTHR 256
#define SLICES 8   // attn_outproj: blocks per batch, each owns 96 out-proj cols

typedef __attribute__((ext_vector_type(8))) short bf16x8;
typedef __attribute__((ext_vector_type(4))) float f32x4;

__device__ __forceinline__ unsigned short f2bf_rne(float f) {
    unsigned int u = __float_as_uint(f);
    u += 0x7FFF + ((u >> 16) & 1);   // round-to-nearest-even
    return (unsigned short)(u >> 16);
}

// ---------------------------------------------------------------------------
// Trilinear sample of one (b,p) point -> sampled[u*E..), bf16. (R6-verified)
// ---------------------------------------------------------------------------
__device__ __forceinline__ void sample_one(
    const float* x, const float* bcrd, const float* offs, int G,
    unsigned short* sampled, int u, int P, int fullN, int t, int tstep)
{
    int b = u / P, p = u % P;
    float gm1 = (float)(G - 1);

    float cx = bcrd[p * 3 + 0] + offs[u * 3 + 0];
    float cy = bcrd[p * 3 + 1] + offs[u * 3 + 1];
    float cz = bcrd[p * 3 + 2] + offs[u * 3 + 2];
    cx = fminf(fmaxf(cx, -1.f), 1.f);
    cy = fminf(fmaxf(cy, -1.f), 1.f);
    cz = fminf(fmaxf(cz, -1.f), 1.f);

    float ix = (cx + 1.f) * 0.5f * gm1;
    float iy = (cy + 1.f) * 0.5f * gm1;
    float iz = (cz + 1.f) * 0.5f * gm1;
    float fx = floorf(ix), fy = floorf(iy), fz = floorf(iz);
    float wx = ix - fx, wy = iy - fy, wz = iz - fz;

    int x0 = (int)fminf(fmaxf(fx,       0.f), gm1);
    int x1 = (int)fminf(fmaxf(fx + 1.f, 0.f), gm1);
    int y0 = (int)fminf(fmaxf(fy,       0.f), gm1);
    int y1 = (int)fminf(fmaxf(fy + 1.f, 0.f), gm1);
    int z0 = (int)fminf(fmaxf(fz,       0.f), gm1);
    int z1 = (int)fminf(fmaxf(fz + 1.f, 0.f), gm1);

    int tk[8];
    tk[0] = (z0 * G + y0) * G + x0;
    tk[1] = (z0 * G + y0) * G + x1;
    tk[2] = (z0 * G + y1) * G + x0;
    tk[3] = (z0 * G + y1) * G + x1;
    tk[4] = (z1 * G + y0) * G + x0;
    tk[5] = (z1 * G + y0) * G + x1;
    tk[6] = (z1 * G + y1) * G + x0;
    tk[7] = (z1 * G + y1) * G + x1;
    float wgt[8];
    wgt[0] = (1.f - wz) * (1.f - wy) * (1.f - wx);
    wgt[1] = (1.f - wz) * (1.f - wy) * wx;
    wgt[2] = (1.f - wz) * wy * (1.f - wx);
    wgt[3] = (1.f - wz) * wy * wx;
    wgt[4] = wz * (1.f - wy) * (1.f - wx);
    wgt[5] = wz * (1.f - wy) * wx;
    wgt[6] = wz * wy * (1.f - wx);
    wgt[7] = wz * wy * wx;

    const float4* xb4 = (const float4*)(x + ((size_t)b * fullN + 1) * E);
    ushort4* outp = (ushort4*)(sampled + (size_t)u * E);
    for (int c4 = t; c4 < E / 4; c4 += tstep) {
        float4 acc = {0.f, 0.f, 0.f, 0.f};
#pragma unroll
        for (int k = 0; k < 8; ++k) {
            float4 v = xb4[(size_t)tk[k] * (E / 4) + c4];
            acc.x += wgt[k] * v.x; acc.y += wgt[k] * v.y;
            acc.z += wgt[k] * v.z; acc.w += wgt[k] * v.w;
        }
        ushort4 o;
        o.x = f2bf_rne(acc.x); o.y = f2bf_rne(acc.y);
        o.z = f2bf_rne(acc.z); o.w = f2bf_rne(acc.w);
        outp[c4] = o;
    }
}

// ---------------------------------------------------------------------------
// 64x64 bf16 MFMA NT tile, fp32 out (R6-verified structure).
// ---------------------------------------------------------------------------
__device__ __forceinline__ void gemm64_tile(
    const unsigned short* A, const unsigned short* W,
    const float* bias, float* C,
    int N, int K, int m0, int n0,
    unsigned short* lsA, unsigned short* lsB)
{
    int wv = threadIdx.x >> 6;
    int ln = threadIdx.x & 63;
    int wm = (wv & 1) * 32;
    int wn = (wv >> 1) * 32;

    f32x4 acc[2][2] = {};

    int srow = ln >> 2;        // 0..15
    int scol = (ln & 3) * 8;   // 0,8,16,24

    for (int k0 = 0; k0 < K; k0 += 32) {
        int row = wv * 16 + srow;
        const unsigned short* ga = A + (size_t)(m0 + row) * K + k0 + scol;
        const unsigned short* gw = W + (size_t)(n0 + row) * K + k0 + scol;
        __builtin_amdgcn_global_load_lds(
            (const __attribute__((address_space(1))) unsigned int*)ga,
            (__attribute__((address_space(3))) unsigned int*)(lsA + wv * 16 * 32),
            16, 0, 0);
        __builtin_amdgcn_global_load_lds(
            (const __attribute__((address_space(1))) unsigned int*)gw,
            (__attribute__((address_space(3))) unsigned int*)(lsB + wv * 16 * 32),
            16, 0, 0);
        __syncthreads();

        int kq = (ln >> 4) * 8;
        int rsel = ln & 15;
        bf16x8 af[2], bfr[2];
#pragma unroll
        for (int i = 0; i < 2; ++i) {
            af[i]  = *(const bf16x8*)&lsA[(wm + i * 16 + rsel) * 32 + kq];
            bfr[i] = *(const bf16x8*)&lsB[(wn + i * 16 + rsel) * 32 + kq];
        }
#pragma unroll
        for (int i = 0; i < 2; ++i)
#pragma unroll
            for (int j = 0; j < 2; ++j)
                acc[i][j] = __builtin_amdgcn_mfma_f32_16x16x32_bf16(
                    af[i], bfr[j], acc[i][j], 0, 0, 0);
        __syncthreads();
    }

    int cr = (ln >> 4) * 4;
    int cc = ln & 15;
#pragma unroll
    for (int j = 0; j < 2; ++j) {
        int col = n0 + wn + j * 16 + cc;
        float bv = bias[col];
#pragma unroll
        for (int i = 0; i < 2; ++i) {
#pragma unroll
            for (int r = 0; r < 4; ++r) {
                int row = m0 + wm + i * 16 + cr + r;
                C[(size_t)row * N + col] = acc[i][j][r] + bv;
            }
        }
    }
}

// ---------------------------------------------------------------------------
// W2 tile: W2[n0+64)[k0+64) = Wkv[n,:] @ spw[:,k], bf16 out. (R6-verified)
// ---------------------------------------------------------------------------
__device__ __forceinline__ void w2_tile(
    const float* Wkv, const float* spw, unsigned short* w2_bf,
    int n0, int k0, unsigned short* lsA, unsigned short* lsB)
{
    int t = threadIdx.x;
    int wv = t >> 6;
    int ln = t & 63;
    int wm = (wv & 1) * 32;
    int wn = (wv >> 1) * 32;

    f32x4 acc[2][2] = {};

    for (int j0 = 0; j0 < E; j0 += 32) {
#pragma unroll
        for (int rep = 0; rep < 2; ++rep) {
            int fi = t + rep * 256;
            int r = fi >> 3, c4 = fi & 7;
            float4 v = *(const float4*)(Wkv + (size_t)(n0 + r) * E + j0 + c4 * 4);
            ushort4 o;
            o.x = f2bf_rne(v.x); o.y = f2bf_rne(v.y);
            o.z = f2bf_rne(v.z); o.w = f2bf_rne(v.w);
            *(ushort4*)(lsA + r * 32 + c4 * 4) = o;
        }
#pragma unroll
        for (int rep = 0; rep < 2; ++rep) {
            int fi = t + rep * 256;
            int kk = fi >> 3, j4 = fi & 7;
            const float* sp = spw + (size_t)(j0 + j4 * 4) * E + k0 + kk;
            ushort4 o;
            o.x = f2bf_rne(sp[0 * E]);
            o.y = f2bf_rne(sp[1 * E]);
            o.z = f2bf_rne(sp[2 * E]);
            o.w = f2bf_rne(sp[3 * E]);
            *(ushort4*)(lsB + kk * 32 + j4 * 4) = o;
        }
        __syncthreads();

        int kq = (ln >> 4) * 8;
        int rsel = ln & 15;
        bf16x8 af[2], bfr[2];
#pragma unroll
        for (int i = 0; i < 2; ++i) {
            af[i]  = *(const bf16x8*)&lsA[(wm + i * 16 + rsel) * 32 + kq];
            bfr[i] = *(const bf16x8*)&lsB[(wn + i * 16 + rsel) * 32 + kq];
        }
#pragma unroll
        for (int i = 0; i < 2; ++i)
#pragma unroll
            for (int j = 0; j < 2; ++j)
                acc[i][j] = __builtin_amdgcn_mfma_f32_16x16x32_bf16(
                    af[i], bfr[j], acc[i][j], 0, 0, 0);
        __syncthreads();
    }

    int cr = (ln >> 4) * 4;
    int cc = ln & 15;
#pragma unroll
    for (int j = 0; j < 2; ++j) {
        int col = k0 + wn + j * 16 + cc;
#pragma unroll
        for (int i = 0; i < 2; ++i) {
#pragma unroll
            for (int r = 0; r < 4; ++r) {
                int row = n0 + wm + i * 16 + cr + r;
                w2_bf[(size_t)row * E + col] = f2bf_rne(acc[i][j][r]);
            }
        }
    }
}

// Generic (rolled) wave dot — fallback path only.
__device__ __forceinline__ void matvec_wave(
    const float* A, const float* W, const float* bias, float* C,
    int u, int N, int K, int ln)
{
    int m = u / N, n = u % N;
    const float* a = A + (size_t)m * K;
    const float* w = W + (size_t)n * K;
    float s = 0.f;
    for (int k = ln; k < K; k += 64) s += a[k] * w[k];
#pragma unroll
    for (int off = 32; off; off >>= 1) s += __shfl_down(s, off);
    if (ln == 0) C[u] = s + bias[n];
}

// Vectorized wave dot for K==768 (R6-verified): 3 independent float4 loads
// per operand, explicitly unrolled.
__device__ __forceinline__ void matvec_wave_v4(
    const float* A, const float* W, const float* bias, float* C,
    int u, int N, int ln)
{
    int m = u / N, n = u % N;
    const float4* a4 = (const float4*)(A + (size_t)m * E);
    const float4* w4 = (const float4*)(W + (size_t)n * E);
    float s = 0.f;
#pragma unroll
    for (int j = 0; j < 3; ++j) {
        float4 av = a4[ln + 64 * j];
        float4 wv = w4[ln + 64 * j];
        s += av.x * wv.x + av.y * wv.y + av.z * wv.z + av.w * wv.w;
    }
#pragma unroll
    for (int off = 32; off; off >>= 1) s += __shfl_down(s, off);
    if (ln == 0) C[u] = s + bias[n];
}

// ---------------------------------------------------------------------------
// K1 "prep": sampling + W2 GEMM + q-proj + b2, all independent segments.
// (R6-verified)
// ---------------------------------------------------------------------------
__global__ __launch_bounds__(256) void prep_kernel(
    const float* __restrict__ x,
    const float* __restrict__ bcrd, const float* __restrict__ offs,
    const int* __restrict__ gsize,
    const float* __restrict__ bio,
    const float* __restrict__ spw, const float* __restrict__ spb,
    const float* __restrict__ ipw, const float* __restrict__ ipb,
    unsigned short* __restrict__ sampled_bf, unsigned short* __restrict__ w2_bf,
    float* __restrict__ q, float* __restrict__ b2,
    int B, int P, int fullN, int nb_sample, int nb_w2, int nb_q)
{
    __shared__ unsigned short lsA[64 * 32];
    __shared__ unsigned short lsB[64 * 32];

    int blk = blockIdx.x;
    int t = threadIdx.x;
    int wv = t >> 6, ln = t & 63;
    const float* Wkv = ipw + (size_t)E * E;

    if (blk < nb_sample) {
        sample_one(x, bcrd, offs, *gsize, sampled_bf, blk, P, fullN, t, NTHR);
        return;
    }
    blk -= nb_sample;
    if (blk < nb_w2) {
        w2_tile(Wkv, spw, w2_bf, (blk / 12) * 64, (blk % 12) * 64, lsA, lsB);
        return;
    }
    blk -= nb_w2;
    if (blk < nb_q) {
        int u = blk * 4 + wv;
        if (u < B * E) matvec_wave_v4(bio, ipw, ipb, q, u, E, ln);
        return;
    }
    blk -= nb_q;
    {
        int u = blk * 4 + wv;
        if (u < 2 * E) matvec_wave_v4(spb, Wkv, ipb + E, b2, u, 2 * E, ln);
    }
}

// ---------------------------------------------------------------------------
// K2: kv = sampled_bf @ W2^T + b2   (2048 x 1536, K=768, fp32 out)
// ---------------------------------------------------------------------------
__global__ __launch_bounds__(256) void kv_gemm(
    const unsigned short* __restrict__ A,
    const unsigned short* __restrict__ W,
    const float* __restrict__ bias,
    float* __restrict__ C, int N, int K)
{
    __shared__ unsigned short lsA[64 * 32];
    __shared__ unsigned short lsB[64 * 32];
    gemm64_tile(A, W, bias, C, N, K, blockIdx.y * 64, blockIdx.x * 64, lsA, lsB);
}

// ---------------------------------------------------------------------------
// K3 "attn_outproj": 512 blocks (b x 8 slices). Attention is redundant per
// slice (cheap: ~200KB L2/block); out-proj is SLICED — each wave does only
// 24 vectorized dots over its 96-col slice (opw one-pass aggregate, 147MB
// L2 total, vs R6's 8x-redundant full-768 which hit the per-CU L2 port for
// ~160us). aout written to d_ws (96 floats/block).
// ---------------------------------------------------------------------------
__global__ __launch_bounds__(256) void attn_outproj(
    const float* __restrict__ q, const float* __restrict__ kv,
    const float* __restrict__ opw, const float* __restrict__ opb,
    float* __restrict__ aout, int B, int P)
{
    __shared__ __align__(16) float q_lds[E];
    __shared__ __align__(16) float ctx_lds[E];

    int b = blockIdx.x % B;         // consecutive blocks -> different XCDs
    int g = blockIdx.x / B;         // 0..SLICES-1 column slice
    int t = threadIdx.x, wv = t >> 6, ln = t & 63;

    const float* kvb = kv + (size_t)b * P * (2 * E);

    // stage q[b] (768 floats, coalesced)
    for (int i = t; i < E; i += NTHR) q_lds[i] = q[(size_t)b * E + i];
    __syncthreads();

    // ---- attention: wave wv handles heads wv, wv+4, wv+8 (R6-verified) ----
    for (int h = wv; h < NH; h += 4) {
        int krow = (ln < P) ? ln : 0;
        const float4* kr4 = (const float4*)(kvb + (size_t)krow * (2 * E) + h * HD);
        const float* qh = q_lds + h * HD;
        float accd = 0.f;
#pragma unroll
        for (int j = 0; j < HD / 4; ++j) {          // 16 independent loads
            float4 k4 = kr4[j];
            accd += qh[4 * j] * k4.x + qh[4 * j + 1] * k4.y
                  + qh[4 * j + 2] * k4.z + qh[4 * j + 3] * k4.w;
        }
        float s = (ln < P) ? accd * 0.125f : -INFINITY;

        float mx = s;
#pragma unroll
        for (int off = 32; off; off >>= 1) mx = fmaxf(mx, __shfl_xor(mx, off));
        float ex = (ln < P) ? __expf(s - mx) : 0.f;
        float den = ex;
#pragma unroll
        for (int off = 32; off; off >>= 1) den += __shfl_xor(den, off);
        float pl = ex / den;

        const float* vcol = kvb + E + h * HD + ln;
        float acc = 0.f;
#pragma unroll
        for (int p = 0; p < 32; ++p)                // 32 independent loads
            acc += __shfl(pl, p) * vcol[(size_t)p * (2 * E)];
        ctx_lds[h * HD + ln] = acc;
    }
    __syncthreads();

    // ---- sliced out-proj: wave wv owns n in [g*96 + wv*24, +24) -----------
    const float4* c4p = (const float4*)ctx_lds;
#pragma unroll 2
    for (int idx = 0; idx < 24; ++idx) {
        int n = g * 96 + wv * 24 + idx;
        const float4* w4 = (const float4*)(opw + (size_t)n * E);
        float s = 0.f;
#pragma unroll
        for (int j = 0; j < 3; ++j) {
            float4 wvv = w4[ln + 64 * j];
            float4 cv = c4p[ln + 64 * j];
            s += wvv.x * cv.x + wvv.y * cv.y + wvv.z * cv.z + wvv.w * cv.w;
        }
#pragma unroll
        for (int off = 32; off; off >>= 1) s += __shfl_down(s, off);
        if (ln == 0) aout[(size_t)b * E + n] = s + opb[n];
    }
}

// ---------------------------------------------------------------------------
// K4 "bcast" (R1-proven, byte-identical): out[b,n,:] = aout[b,:] * conf[b].
// 101 MB coalesced float4; as a standalone kernel this ran under the 61us
// fill threshold in R1 (>1.6 TB/s).
// ---------------------------------------------------------------------------
__global__ void bcast_kernel(const float* __restrict__ attn_out,
                             const float* __restrict__ conf,
                             float* __restrict__ out,
                             int fullN, int pc)
{
    int b = blockIdx.y;
    float cf = conf[b];
    const float4* ao = (const float4*)(attn_out + (size_t)b * E);
    float4* ob = (float4*)(out + (size_t)b * fullN * E);
    int i = blockIdx.x * blockDim.x + threadIdx.x;
    if (i < pc) {
        int c4 = i % (E / 4);
        float4 v = ao[c4];
        v.x *= cf; v.y *= cf; v.z *= cf; v.w *= cf;
        ob[i] = v;
    }
}

// ---------------------------------------------------------------------------
// Fallback tail pieces (used only if d_ws too small for kv): R6-proven.
// ---------------------------------------------------------------------------
__global__ void attn_fb(const float* __restrict__ q,
                        const float* __restrict__ kv,
                        float* __restrict__ ctx, int B, int P)
{
    int u = blockIdx.x * 4 + (threadIdx.x >> 6);
    int ln = threadIdx.x & 63;
    if (u >= B * NH) return;
    int b = u / NH, h = u % NH;
    float qd = q[(size_t)b * E + h * HD + ln];
    const float* kvb = kv + (size_t)b * P * (2 * E);
    int krow = (ln < P) ? ln : 0;
    const float* kr = kvb + (size_t)krow * (2 * E) + h * HD;
    float accd = 0.f;
#pragma unroll
    for (int e = 0; e < HD; ++e) accd += __shfl(qd, e) * kr[e];
    float s = (ln < P) ? accd * 0.125f : -INFINITY;
    float mx = s;
#pragma unroll
    for (int off = 32; off; off >>= 1) mx = fmaxf(mx, __shfl_xor(mx, off));
    float ex = (ln < P) ? __expf(s - mx) : 0.f;
    float den = ex;
#pragma unroll
    for (int off = 32; off; off >>= 1) den += __shfl_xor(den, off);
    float pl = ex / den;
    float acc = 0.f;
    for (int p = 0; p < P; ++p)
        acc += __shfl(pl, p) * kvb[(size_t)p * (2 * E) + E + h * HD + ln];
    ctx[(size_t)b * E + h * HD + ln] = acc;
}

__global__ void matvec_fb(const float* __restrict__ A,
                          const float* __restrict__ W,
                          const float* __restrict__ bias,
                          float* __restrict__ C, int M, int N, int K)
{
    int u = blockIdx.x * 4 + (threadIdx.x >> 6);
    if (u < M * N) matvec_wave(A, W, bias, C, u, N, K, threadIdx.x & 63);
}

// ---------------------------------------------------------------------------
extern "C" void kernel_launch(void* const* d_in, const int* in_sizes, int n_in,
                              void* d_out, int out_size, void* d_ws, size_t ws_size,
                              hipStream_t stream)
{
    const float* x      = (const float*)d_in[0];
    const float* bio    = (const float*)d_in[1];
    const float* bcrd   = (const float*)d_in[2];
    const float* offs   = (const float*)d_in[3];
    const float* conf   = (const float*)d_in[4];
    const float* spw    = (const float*)d_in[5];
    const float* spb    = (const float*)d_in[6];
    const float* ipw    = (const float*)d_in[7];
    const float* ipb    = (const float*)d_in[8];
    const float* opw    = (const float*)d_in[9];
    const float* opb    = (const float*)d_in[10];
    const int*   gsize  = (const int*)d_in[11];
    float* out = (float*)d_out;

    int B     = in_sizes[1] / E;            // 64
    int P     = in_sizes[2] / 3;            // 32
    int fullN = in_sizes[0] / (B * E);      // 513
    int M     = B * P;                      // 2048

    // sampled_bf / w2_bf live in d_out's front (read only by K1/K2; final
    // bcast overwrites all of d_out last).
    char* base = (char*)d_out;
    unsigned short* sampled_bf = (unsigned short*)(base + 0);          // 3.0 MB
    unsigned short* w2_bf      = (unsigned short*)(base + 3145728);    // 2.25 MB

    const size_t kv_bytes = (size_t)M * (2 * E) * 4;        // 12,582,912
    const size_t q_bytes  = (size_t)B * E * 4;              // 196,608
    const size_t b2_bytes = (size_t)(2 * E) * 4;            // 6,144
    const size_t ao_bytes = (size_t)B * E * 4;              // 196,608
    const bool path_a = (ws_size >= kv_bytes + q_bytes + b2_bytes + ao_bytes);

    float *kv, *q, *b2, *aout;
    if (path_a) {
        kv   = (float*)d_ws;
        q    = (float*)((char*)d_ws + kv_bytes);
        b2   = (float*)((char*)d_ws + kv_bytes + q_bytes);
        aout = (float*)((char*)d_ws + kv_bytes + q_bytes + b2_bytes);
    } else {
        kv   = (float*)(base + 5505024);                    // 12.6 MB
        q    = (float*)(base + 18087936);                   // 192 KB
        b2   = (float*)(base + 18481152);                   // 6 KB
        aout = (float*)d_ws;                                // 192 KB
    }

    // K1: prep (sample + W2 GEMM + q-proj + b2)
    int nb_sample = M;                       // 2048
    int nb_w2     = (2 * E / 64) * (E / 64); // 288
    int nb_q      = (B * E + 3) / 4;         // 12288
    int nb_b2     = (2 * E + 3) / 4;         // 384
    prep_kernel<<<nb_sample + nb_w2 + nb_q + nb_b2, NTHR, 0, stream>>>(
        x, bcrd, offs, gsize, bio, spw, spb, ipw, ipb,
        sampled_bf, w2_bf, q, b2, B, P, fullN, nb_sample, nb_w2, nb_q);

    // K2: kv = sampled @ W2^T + b2
    kv_gemm<<<dim3(2 * E / 64, M / 64), NTHR, 0, stream>>>(
        sampled_bf, w2_bf, b2, kv, 2 * E, E);

    if (path_a) {
        // K3: attention + sliced out-proj -> aout (d_ws)
        attn_outproj<<<B * SLICES, NTHR, 0, stream>>>(q, kv, opw, opb, aout,
                                                      B, P);
    } else {
        float* ctx = (float*)(base + 18284544);
        attn_fb<<<(B * NH + 3) / 4, NTHR, 0, stream>>>(q, kv, ctx, B, P);
        matvec_fb<<<(B * E + 3) / 4, NTHR, 0, stream>>>(ctx, opw, opb, aout,
                                                        B, E, E);
    }

    // K4: broadcast * confidence (overwrites every element of d_out)
    int pc = fullN * E / 4;
    bcast_kernel<<<dim3((pc + 255) / 256, B), NTHR, 0, stream>>>(
        aout, conf, out, fullN, pc);
}

// Round 8
// 270.524 us; speedup vs baseline: 4.1788x; 1.0031x over previous
//
#include <hip/hip_runtime.h>
#include <hip/hip_bf16.h>
#include <math.h>

#define E 768
#define NH 12
#define HD 64
#define NTHR 256
#define SLICES 8   // outproj: blocks per batch, each owns 96 out-proj cols

typedef __attribute__((ext_vector_type(8))) short bf16x8;
typedef __attribute__((ext_vector_type(4))) float f32x4;

__device__ __forceinline__ unsigned short f2bf_rne(float f) {
    unsigned int u = __float_as_uint(f);
    u += 0x7FFF + ((u >> 16) & 1);   // round-to-nearest-even
    return (unsigned short)(u >> 16);
}

__device__ __forceinline__ float bf2f(unsigned short u) {
    return __uint_as_float((unsigned)u << 16);
}

// ---------------------------------------------------------------------------
// Trilinear sample of one (b,p) point -> sampled[u*E..), bf16. (R7-verified)
// ---------------------------------------------------------------------------
__device__ __forceinline__ void sample_one(
    const float* x, const float* bcrd, const float* offs, int G,
    unsigned short* sampled, int u, int P, int fullN, int t, int tstep)
{
    int b = u / P, p = u % P;
    float gm1 = (float)(G - 1);

    float cx = bcrd[p * 3 + 0] + offs[u * 3 + 0];
    float cy = bcrd[p * 3 + 1] + offs[u * 3 + 1];
    float cz = bcrd[p * 3 + 2] + offs[u * 3 + 2];
    cx = fminf(fmaxf(cx, -1.f), 1.f);
    cy = fminf(fmaxf(cy, -1.f), 1.f);
    cz = fminf(fmaxf(cz, -1.f), 1.f);

    float ix = (cx + 1.f) * 0.5f * gm1;
    float iy = (cy + 1.f) * 0.5f * gm1;
    float iz = (cz + 1.f) * 0.5f * gm1;
    float fx = floorf(ix), fy = floorf(iy), fz = floorf(iz);
    float wx = ix - fx, wy = iy - fy, wz = iz - fz;

    int x0 = (int)fminf(fmaxf(fx,       0.f), gm1);
    int x1 = (int)fminf(fmaxf(fx + 1.f, 0.f), gm1);
    int y0 = (int)fminf(fmaxf(fy,       0.f), gm1);
    int y1 = (int)fminf(fmaxf(fy + 1.f, 0.f), gm1);
    int z0 = (int)fminf(fmaxf(fz,       0.f), gm1);
    int z1 = (int)fminf(fmaxf(fz + 1.f, 0.f), gm1);

    int tk[8];
    tk[0] = (z0 * G + y0) * G + x0;
    tk[1] = (z0 * G + y0) * G + x1;
    tk[2] = (z0 * G + y1) * G + x0;
    tk[3] = (z0 * G + y1) * G + x1;
    tk[4] = (z1 * G + y0) * G + x0;
    tk[5] = (z1 * G + y0) * G + x1;
    tk[6] = (z1 * G + y1) * G + x0;
    tk[7] = (z1 * G + y1) * G + x1;
    float wgt[8];
    wgt[0] = (1.f - wz) * (1.f - wy) * (1.f - wx);
    wgt[1] = (1.f - wz) * (1.f - wy) * wx;
    wgt[2] = (1.f - wz) * wy * (1.f - wx);
    wgt[3] = (1.f - wz) * wy * wx;
    wgt[4] = wz * (1.f - wy) * (1.f - wx);
    wgt[5] = wz * (1.f - wy) * wx;
    wgt[6] = wz * wy * (1.f - wx);
    wgt[7] = wz * wy * wx;

    const float4* xb4 = (const float4*)(x + ((size_t)b * fullN + 1) * E);
    ushort4* outp = (ushort4*)(sampled + (size_t)u * E);
    for (int c4 = t; c4 < E / 4; c4 += tstep) {
        float4 acc = {0.f, 0.f, 0.f, 0.f};
#pragma unroll
        for (int k = 0; k < 8; ++k) {
            float4 v = xb4[(size_t)tk[k] * (E / 4) + c4];
            acc.x += wgt[k] * v.x; acc.y += wgt[k] * v.y;
            acc.z += wgt[k] * v.z; acc.w += wgt[k] * v.w;
        }
        ushort4 o;
        o.x = f2bf_rne(acc.x); o.y = f2bf_rne(acc.y);
        o.z = f2bf_rne(acc.z); o.w = f2bf_rne(acc.w);
        outp[c4] = o;
    }
}

// ---------------------------------------------------------------------------
// W2 tile: W2[n0+64)[k0+64) = Wkv[n,:] @ spw[:,k], bf16 out. (R7-verified)
// ---------------------------------------------------------------------------
__device__ __forceinline__ void w2_tile(
    const float* Wkv, const float* spw, unsigned short* w2_bf,
    int n0, int k0, unsigned short* lsA, unsigned short* lsB)
{
    int t = threadIdx.x;
    int wv = t >> 6;
    int ln = t & 63;
    int wm = (wv & 1) * 32;
    int wn = (wv >> 1) * 32;

    f32x4 acc[2][2] = {};

    for (int j0 = 0; j0 < E; j0 += 32) {
#pragma unroll
        for (int rep = 0; rep < 2; ++rep) {
            int fi = t + rep * 256;
            int r = fi >> 3, c4 = fi & 7;
            float4 v = *(const float4*)(Wkv + (size_t)(n0 + r) * E + j0 + c4 * 4);
            ushort4 o;
            o.x = f2bf_rne(v.x); o.y = f2bf_rne(v.y);
            o.z = f2bf_rne(v.z); o.w = f2bf_rne(v.w);
            *(ushort4*)(lsA + r * 32 + c4 * 4) = o;
        }
#pragma unroll
        for (int rep = 0; rep < 2; ++rep) {
            int fi = t + rep * 256;
            int kk = fi >> 3, j4 = fi & 7;
            const float* sp = spw + (size_t)(j0 + j4 * 4) * E + k0 + kk;
            ushort4 o;
            o.x = f2bf_rne(sp[0 * E]);
            o.y = f2bf_rne(sp[1 * E]);
            o.z = f2bf_rne(sp[2 * E]);
            o.w = f2bf_rne(sp[3 * E]);
            *(ushort4*)(lsB + kk * 32 + j4 * 4) = o;
        }
        __syncthreads();

        int kq = (ln >> 4) * 8;
        int rsel = ln & 15;
        bf16x8 af[2], bfr[2];
#pragma unroll
        for (int i = 0; i < 2; ++i) {
            af[i]  = *(const bf16x8*)&lsA[(wm + i * 16 + rsel) * 32 + kq];
            bfr[i] = *(const bf16x8*)&lsB[(wn + i * 16 + rsel) * 32 + kq];
        }
#pragma unroll
        for (int i = 0; i < 2; ++i)
#pragma unroll
            for (int j = 0; j < 2; ++j)
                acc[i][j] = __builtin_amdgcn_mfma_f32_16x16x32_bf16(
                    af[i], bfr[j], acc[i][j], 0, 0, 0);
        __syncthreads();
    }

    int cr = (ln >> 4) * 4;
    int cc = ln & 15;
#pragma unroll
    for (int j = 0; j < 2; ++j) {
        int col = k0 + wn + j * 16 + cc;
#pragma unroll
        for (int i = 0; i < 2; ++i) {
#pragma unroll
            for (int r = 0; r < 4; ++r) {
                int row = n0 + wm + i * 16 + cr + r;
                w2_bf[(size_t)row * E + col] = f2bf_rne(acc[i][j][r]);
            }
        }
    }
}

// Vectorized wave dot for K==768 (R7-verified): 3 independent float4 loads
// per operand, explicitly unrolled.
__device__ __forceinline__ void matvec_wave_v4(
    const float* A, const float* W, const float* bias, float* C,
    int u, int N, int ln)
{
    int m = u / N, n = u % N;
    const float4* a4 = (const float4*)(A + (size_t)m * E);
    const float4* w4 = (const float4*)(W + (size_t)n * E);
    float s = 0.f;
#pragma unroll
    for (int j = 0; j < 3; ++j) {
        float4 av = a4[ln + 64 * j];
        float4 wv = w4[ln + 64 * j];
        s += av.x * wv.x + av.y * wv.y + av.z * wv.z + av.w * wv.w;
    }
#pragma unroll
    for (int off = 32; off; off >>= 1) s += __shfl_down(s, off);
    if (ln == 0) C[u] = s + bias[n];
}

// ---------------------------------------------------------------------------
// K1 "prep": sampling + W2 GEMM + q-proj + b2, all independent segments.
// (R7-verified)
// ---------------------------------------------------------------------------
__global__ __launch_bounds__(256) void prep_kernel(
    const float* __restrict__ x,
    const float* __restrict__ bcrd, const float* __restrict__ offs,
    const int* __restrict__ gsize,
    const float* __restrict__ bio,
    const float* __restrict__ spw, const float* __restrict__ spb,
    const float* __restrict__ ipw, const float* __restrict__ ipb,
    unsigned short* __restrict__ sampled_bf, unsigned short* __restrict__ w2_bf,
    float* __restrict__ q, float* __restrict__ b2,
    int B, int P, int fullN, int nb_sample, int nb_w2, int nb_q)
{
    __shared__ unsigned short lsA[64 * 32];
    __shared__ unsigned short lsB[64 * 32];

    int blk = blockIdx.x;
    int t = threadIdx.x;
    int wv = t >> 6, ln = t & 63;
    const float* Wkv = ipw + (size_t)E * E;

    if (blk < nb_sample) {
        sample_one(x, bcrd, offs, *gsize, sampled_bf, blk, P, fullN, t, NTHR);
        return;
    }
    blk -= nb_sample;
    if (blk < nb_w2) {
        w2_tile(Wkv, spw, w2_bf, (blk / 12) * 64, (blk % 12) * 64, lsA, lsB);
        return;
    }
    blk -= nb_w2;
    if (blk < nb_q) {
        int u = blk * 4 + wv;
        if (u < B * E) matvec_wave_v4(bio, ipw, ipb, q, u, E, ln);
        return;
    }
    blk -= nb_q;
    {
        int u = blk * 4 + wv;
        if (u < 2 * E) matvec_wave_v4(spb, Wkv, ipb + E, b2, u, 2 * E, ln);
    }
}

// ---------------------------------------------------------------------------
// K2 "attn_ctx": per-(b,h) fused attention WITHOUT materializing kv.
//   u[j]    = sum_d W2k[h*64+d][j] * q[b,h*64+d]      (k-bias cancels in SM)
//   s[p]    = 0.125 * sum_j u[j] * sampled[b,p,j]
//   attn    = softmax_p(s)
//   ctxs[j] = sum_p attn[p] * sampled[b,p,j]
//   ctx[d]  = sum_j W2v[h*64+d][j] * ctxs[j] + b2v[h*64+d]   (sum attn = 1)
// Replaces kv_gemm's 4.83 GFLOP with ~0.15 GFLOP of coalesced L2 reads.
// 768 blocks (h-major grid), ~7 KB LDS.
// ---------------------------------------------------------------------------
__global__ __launch_bounds__(256) void attn_ctx(
    const float* __restrict__ q, const unsigned short* __restrict__ sampled_bf,
    const unsigned short* __restrict__ w2_bf, const float* __restrict__ b2,
    float* __restrict__ ctx, int B, int P)
{
    __shared__ float q_lds[HD];
    __shared__ __align__(16) float u_lds[E];
    __shared__ float sc_lds[64];
    __shared__ float at_lds[64];
    __shared__ __align__(16) float cx_lds[E];

    int b = blockIdx.x % B;
    int h = blockIdx.x / B;
    int t = threadIdx.x, wv = t >> 6, ln = t & 63;

    const unsigned short* W2k = w2_bf + (size_t)(h * HD) * E;
    const unsigned short* W2v = w2_bf + (size_t)(E + h * HD) * E;
    const unsigned short* smp = sampled_bf + (size_t)(b * P) * E;

    if (t < HD) q_lds[t] = q[(size_t)b * E + h * HD + t];
    __syncthreads();

    // ---- u[j], thread t < 192 owns j = 4t..4t+3 (ushort4 per row) ---------
    if (t < E / 4) {
        float4 uu = {0.f, 0.f, 0.f, 0.f};
        for (int d = 0; d < HD; ++d) {
            float qd = q_lds[d];
            ushort4 r = *(const ushort4*)(W2k + (size_t)d * E + 4 * t);
            uu.x += qd * bf2f(r.x); uu.y += qd * bf2f(r.y);
            uu.z += qd * bf2f(r.z); uu.w += qd * bf2f(r.w);
        }
        *(float4*)&u_lds[4 * t] = uu;
    }
    __syncthreads();

    // ---- scores: wave wv handles p = wv, wv+4, ... (coalesced bf16 reads) -
    for (int p = wv; p < P; p += 4) {
        const unsigned short* sr = smp + (size_t)p * E;
        float s = 0.f;
#pragma unroll
        for (int c = 0; c < E / 64; ++c)
            s += u_lds[ln + 64 * c] * bf2f(sr[ln + 64 * c]);
#pragma unroll
        for (int off = 32; off; off >>= 1) s += __shfl_xor(s, off);
        if (ln == 0) sc_lds[p] = s * 0.125f;
    }
    __syncthreads();

    // ---- softmax over P (wave 0; all-lane shuffles, clamped) --------------
    if (wv == 0) {
        float s = (ln < P) ? sc_lds[ln] : -INFINITY;
        float mx = s;
#pragma unroll
        for (int off = 32; off; off >>= 1) mx = fmaxf(mx, __shfl_xor(mx, off));
        float ex = (ln < P) ? __expf(s - mx) : 0.f;
        float den = ex;
#pragma unroll
        for (int off = 32; off; off >>= 1) den += __shfl_xor(den, off);
        if (ln < P) at_lds[ln] = ex / den;
    }
    __syncthreads();

    // ---- ctxs[j]: thread t < 192 owns j = 4t..4t+3 ------------------------
    if (t < E / 4) {
        float4 cc = {0.f, 0.f, 0.f, 0.f};
        for (int p = 0; p < P; ++p) {
            float a = at_lds[p];
            ushort4 r = *(const ushort4*)(smp + (size_t)p * E + 4 * t);
            cc.x += a * bf2f(r.x); cc.y += a * bf2f(r.y);
            cc.z += a * bf2f(r.z); cc.w += a * bf2f(r.w);
        }
        *(float4*)&cx_lds[4 * t] = cc;
    }
    __syncthreads();

    // ---- ctx[d]: wave wv owns d = wv, wv+4, ... (16 wave-dots each) -------
    for (int d = wv; d < HD; d += 4) {
        const unsigned short* vr = W2v + (size_t)d * E;
        float s = 0.f;
#pragma unroll
        for (int c = 0; c < E / 64; ++c)
            s += cx_lds[ln + 64 * c] * bf2f(vr[ln + 64 * c]);
#pragma unroll
        for (int off = 32; off; off >>= 1) s += __shfl_down(s, off);
        if (ln == 0)
            ctx[(size_t)b * E + h * HD + d] = s + b2[E + h * HD + d];
    }
}

// ---------------------------------------------------------------------------
// K3 "outproj": 512 blocks (b x 8 slices); sliced vectorized dots
// (R7-verified pattern), ctx staged from d_ws.
// ---------------------------------------------------------------------------
__global__ __launch_bounds__(256) void outproj_kernel(
    const float* __restrict__ ctx, const float* __restrict__ opw,
    const float* __restrict__ opb, float* __restrict__ aout, int B)
{
    __shared__ __align__(16) float ctx_lds[E];

    int b = blockIdx.x % B;
    int g = blockIdx.x / B;
    int t = threadIdx.x, wv = t >> 6, ln = t & 63;

    for (int i = t; i < E; i += NTHR) ctx_lds[i] = ctx[(size_t)b * E + i];
    __syncthreads();

    const float4* c4p = (const float4*)ctx_lds;
#pragma unroll 2
    for (int idx = 0; idx < 24; ++idx) {
        int n = g * 96 + wv * 24 + idx;
        const float4* w4 = (const float4*)(opw + (size_t)n * E);
        float s = 0.f;
#pragma unroll
        for (int j = 0; j < 3; ++j) {
            float4 wvv = w4[ln + 64 * j];
            float4 cv = c4p[ln + 64 * j];
            s += wvv.x * cv.x + wvv.y * cv.y + wvv.z * cv.z + wvv.w * cv.w;
        }
#pragma unroll
        for (int off = 32; off; off >>= 1) s += __shfl_down(s, off);
        if (ln == 0) aout[(size_t)b * E + n] = s + opb[n];
    }
}

// ---------------------------------------------------------------------------
// K4 "bcast" (R7-proven): out[b,n,:] = aout[b,:] * conf[b]. 101 MB coalesced.
// ---------------------------------------------------------------------------
__global__ void bcast_kernel(const float* __restrict__ attn_out,
                             const float* __restrict__ conf,
                             float* __restrict__ out,
                             int fullN, int pc)
{
    int b = blockIdx.y;
    float cf = conf[b];
    const float4* ao = (const float4*)(attn_out + (size_t)b * E);
    float4* ob = (float4*)(out + (size_t)b * fullN * E);
    int i = blockIdx.x * blockDim.x + threadIdx.x;
    if (i < pc) {
        int c4 = i % (E / 4);
        float4 v = ao[c4];
        v.x *= cf; v.y *= cf; v.z *= cf; v.w *= cf;
        ob[i] = v;
    }
}

// ---------------------------------------------------------------------------
extern "C" void kernel_launch(void* const* d_in, const int* in_sizes, int n_in,
                              void* d_out, int out_size, void* d_ws, size_t ws_size,
                              hipStream_t stream)
{
    const float* x      = (const float*)d_in[0];
    const float* bio    = (const float*)d_in[1];
    const float* bcrd   = (const float*)d_in[2];
    const float* offs   = (const float*)d_in[3];
    const float* conf   = (const float*)d_in[4];
    const float* spw    = (const float*)d_in[5];
    const float* spb    = (const float*)d_in[6];
    const float* ipw    = (const float*)d_in[7];
    const float* ipb    = (const float*)d_in[8];
    const float* opw    = (const float*)d_in[9];
    const float* opb    = (const float*)d_in[10];
    const int*   gsize  = (const int*)d_in[11];
    float* out = (float*)d_out;

    int B     = in_sizes[1] / E;            // 64
    int P     = in_sizes[2] / 3;            // 32
    int fullN = in_sizes[0] / (B * E);      // 513
    int M     = B * P;                      // 2048

    // sampled_bf / w2_bf live in d_out's front (read by K1/K2 only; final
    // bcast overwrites all of d_out last).
    char* base = (char*)d_out;
    unsigned short* sampled_bf = (unsigned short*)(base + 0);          // 3.0 MB
    unsigned short* w2_bf      = (unsigned short*)(base + 3145728);    // 2.25 MB

    // d_ws layout (<1 MB total; ws_size >= 13 MB proven in R4 run):
    float* q    = (float*)d_ws;                                // 192 KB
    float* b2   = (float*)((char*)d_ws + 196608);              // 6 KB
    float* ctx  = (float*)((char*)d_ws + 262144);              // 192 KB
    float* aout = (float*)((char*)d_ws + 524288);              // 192 KB

    // K1: prep (sample + W2 GEMM + q-proj + b2)
    int nb_sample = M;                       // 2048
    int nb_w2     = (2 * E / 64) * (E / 64); // 288
    int nb_q      = (B * E + 3) / 4;         // 12288
    int nb_b2     = (2 * E + 3) / 4;         // 384
    prep_kernel<<<nb_sample + nb_w2 + nb_q + nb_b2, NTHR, 0, stream>>>(
        x, bcrd, offs, gsize, bio, spw, spb, ipw, ipb,
        sampled_bf, w2_bf, q, b2, B, P, fullN, nb_sample, nb_w2, nb_q);

    // K2: fused attention directly from sampled + W2 (no kv materialization)
    attn_ctx<<<B * NH, NTHR, 0, stream>>>(q, sampled_bf, w2_bf, b2, ctx, B, P);

    // K3: sliced out-proj -> aout
    outproj_kernel<<<B * SLICES, NTHR, 0, stream>>>(ctx, opw, opb, aout, B);

    // K4: broadcast * confidence (overwrites every element of d_out)
    int pc = fullN * E / 4;
    bcast_kernel<<<dim3((pc + 255) / 256, B), NTHR, 0, stream>>>(
        aout, conf, out, fullN, pc);
}